// Round 2
// baseline (1104.354 us; speedup 1.0000x reference)
//
#include <hip/hip_runtime.h>
#include <cstdint>

typedef unsigned short ushort_t;
typedef __attribute__((ext_vector_type(8))) short short8;
typedef __attribute__((ext_vector_type(4))) float f4;

#define BB   64
#define TT   2048
#define DD   256
#define DO_  128
#define OL   64

// ---- workspace layout (float indices) ----
#define O_TWH   0
#define O_RMAX  131072
#define O_RDEN  131136
#define O_CIP   131200            // 64*16*256 = 262144
#define O_CI    393344            // 64*256
#define O_GIC   409728            // 64*768
#define O_RIC   458880            // 64*128
#define O_S0    467072            // 64*256
#define F_GW    483456            // [j<384][k<256][4] fp32 gate weights = 393216
#define F_RWS   876672            // [j<256][m<128] fp32 = 32768
#define F_RWY   909440            // [jy<128][m<128] fp32 = 16384
#define O_US    925824            // ushort region (bf16 W_h_a), byte ofs 3703296 (16B aligned)
#define U_WB    0                 // 256*256 bf16 of W_h_a (row-major)

static __device__ __forceinline__ ushort_t f2bf(float f) {
  union { float f; uint32_t u; } v; v.f = f;
  uint32_t u = v.u;
  u += 0x7FFFu + ((u >> 16) & 1u);   // RNE (inputs are finite normals)
  return (ushort_t)(u >> 16);
}
static __device__ __forceinline__ float fast_tanh(float x) {
  float e = __expf(2.f * x);
  return 1.f - 2.f / (e + 1.f);
}
static __device__ __forceinline__ float fast_sigmoid(float x) {
  return 1.f / (1.f + __expf(-x));
}

// ---------------- K0: pre-transpose weights ----------------
// elements: 65536 (bf16 Wha) + 393216 (GW) + 32768 (RWS) + 16384 (RWY) = 507904
__global__ __launch_bounds__(256) void k_prep(const float* __restrict__ Wha,
    const float* __restrict__ Whhg, const float* __restrict__ Wihg,
    const float* __restrict__ Wihr, const float* __restrict__ Whhr,
    float* __restrict__ ws, ushort_t* __restrict__ us) {
  int idx = blockIdx.x * 256 + threadIdx.x;   // grid exactly 507904/256 = 1984
  if (idx < 65536) {
    us[U_WB + idx] = f2bf(Wha[idx]);
  } else if (idx < 65536 + 393216) {
    int i = idx - 65536;            // [j<384][k<256][slot<4]
    int slot = i & 3, k = (i >> 2) & 255, j = i >> 10;
    float v = 0.f;
    if (j < 256) {
      if (slot < 3) v = Whhg[(slot * 256 + k) * 256 + j];          // r,z,nh from W_hh_g
    } else {
      int jy = j - 256;
      if (slot < 2)      v = Wihg[(slot * 256 + k) * 384 + 256 + jy]; // r,z from W_ih_g y-part
      else if (slot == 2) v = Wihg[(512 + k) * 384 + 256 + jy];       // ni
    }
    ws[F_GW + i] = v;
  } else if (idx < 65536 + 393216 + 32768) {
    int i = idx - (65536 + 393216); int j = i >> 7, m = i & 127;
    ws[F_RWS + i] = Wihr[m * 512 + 256 + j];
  } else {
    int i = idx - (65536 + 393216 + 32768); int jy = i >> 7, m = i & 127;
    ws[F_RWY + i] = Whhr[m * 128 + jy];
  }
}

// ---------------- K1: twh[b,t] = sum_h tanh(h.Wha^T) * wa1 (MFMA) ----------------
__global__ __launch_bounds__(256) void k_twh(const float* __restrict__ h,
                                             const ushort_t* __restrict__ Wb,
                                             const float* __restrict__ Wa,
                                             float* __restrict__ twh) {
  __shared__ __align__(16) ushort_t alds[64 * 264];
  __shared__ float walds[256];
  const int tid = threadIdx.x;
  const long rowbase = (long)blockIdx.x * 64;
  walds[tid] = Wa[tid];
  for (int it = 0; it < 8; ++it) {
    int q = it * 256 + tid;
    int r = q >> 5;
    int c8 = q & 31;
    const float* src = h + (rowbase + r) * 256 + c8 * 8;
    float4 a = *(const float4*)(src);
    float4 b = *(const float4*)(src + 4);
    union { ushort_t u[8]; short8 v; } t;
    t.u[0]=f2bf(a.x); t.u[1]=f2bf(a.y); t.u[2]=f2bf(a.z); t.u[3]=f2bf(a.w);
    t.u[4]=f2bf(b.x); t.u[5]=f2bf(b.y); t.u[6]=f2bf(b.z); t.u[7]=f2bf(b.w);
    *(short8*)&alds[r * 264 + c8 * 8] = t.v;
  }
  __syncthreads();
  const int l = tid & 63, w = tid >> 6;
  const int cres = l & 15, kg = l >> 4;
  f4 acc[16];
  #pragma unroll
  for (int f = 0; f < 16; ++f) acc[f] = (f4){0.f, 0.f, 0.f, 0.f};
  const int arow = 16 * w + cres;
  #pragma unroll
  for (int ks = 0; ks < 8; ++ks) {
    short8 af = *(const short8*)&alds[arow * 264 + ks * 32 + kg * 8];
    const ushort_t* bp = Wb + ks * 32 + kg * 8 + cres * 256;
    #pragma unroll
    for (int f = 0; f < 16; ++f) {
      short8 bf = *(const short8*)(bp + f * 16 * 256);
      acc[f] = __builtin_amdgcn_mfma_f32_16x16x32_bf16(af, bf, acc[f], 0, 0, 0);
    }
  }
  float t4[4] = {0.f, 0.f, 0.f, 0.f};
  #pragma unroll
  for (int f = 0; f < 16; ++f) {
    float wa = walds[16 * f + cres];
    #pragma unroll
    for (int r = 0; r < 4; ++r) t4[r] += fast_tanh(acc[f][r]) * wa;
  }
  #pragma unroll
  for (int m = 1; m <= 8; m <<= 1) {
    #pragma unroll
    for (int r = 0; r < 4; ++r) t4[r] += __shfl_xor(t4[r], m);
  }
  if (cres == 0) {
    #pragma unroll
    for (int r = 0; r < 4; ++r)
      twh[rowbase + 16 * w + kg * 4 + r] = t4[r];
  }
}

// ---------------- K2a: per-batch softmax stats over T ----------------
__global__ __launch_bounds__(256) void k_stats(const float* __restrict__ twh,
                                               float* __restrict__ rmax,
                                               float* __restrict__ rden) {
  __shared__ float redm[4], reds[4];
  const int b = blockIdx.x, tid = threadIdx.x;
  float v[8];
  #pragma unroll
  for (int j = 0; j < 8; ++j) v[j] = twh[b * 2048 + tid + j * 256];
  float mx = v[0];
  #pragma unroll
  for (int j = 1; j < 8; ++j) mx = fmaxf(mx, v[j]);
  #pragma unroll
  for (int d = 32; d >= 1; d >>= 1) mx = fmaxf(mx, __shfl_xor(mx, d));
  if ((tid & 63) == 0) redm[tid >> 6] = mx;
  __syncthreads();
  float M = fmaxf(fmaxf(redm[0], redm[1]), fmaxf(redm[2], redm[3]));
  float s = 0.f;
  #pragma unroll
  for (int j = 0; j < 8; ++j) s += __expf(v[j] - M);
  #pragma unroll
  for (int d = 32; d >= 1; d >>= 1) s += __shfl_xor(s, d);
  if ((tid & 63) == 0) reds[tid >> 6] = s;
  __syncthreads();
  if (tid == 0) { rmax[b] = M; rden[b] = reds[0] + reds[1] + reds[2] + reds[3]; }
}

// ---------------- K2b: partial ci over t-slices ----------------
__global__ __launch_bounds__(256) void k_cipart(const float* __restrict__ h,
                                                const float* __restrict__ twh,
                                                const float* __restrict__ rmax,
                                                float* __restrict__ cipart) {
  __shared__ float p[128];
  const int b = blockIdx.x >> 4, ts = blockIdx.x & 15;
  const int tid = threadIdx.x;
  const int t0 = ts * 128;
  if (tid < 128) p[tid] = __expf(twh[b * 2048 + t0 + tid] - rmax[b]);
  __syncthreads();
  float acc = 0.f;
  const float* hp = h + ((long)(b * 2048 + t0)) * 256 + tid;
  #pragma unroll 8
  for (int i = 0; i < 128; ++i) { acc += p[i] * hp[0]; hp += 256; }
  cipart[(b * 16 + ts) * 256 + tid] = acc;
}

// ---------------- K2c: reduce partials -> ci ----------------
__global__ __launch_bounds__(256) void k_cired(const float* __restrict__ cipart,
                                               const float* __restrict__ rden,
                                               float* __restrict__ ci) {
  const int b = blockIdx.x, d = threadIdx.x;
  float a = 0.f;
  #pragma unroll
  for (int ts = 0; ts < 16; ++ts) a += cipart[(b * 16 + ts) * 256 + d];
  ci[b * 256 + d] = a / rden[b];
}

// ---------------- K3: per-batch constants (gi_c, ri_c, s0) ----------------
__global__ __launch_bounds__(256) void k_const(const float* __restrict__ h,
    const float* __restrict__ ci,
    const float* __restrict__ Wihg, const float* __restrict__ bihg,
    const float* __restrict__ bhhg,
    const float* __restrict__ Wihr, const float* __restrict__ bihr,
    const float* __restrict__ bhhr,
    const float* __restrict__ Winit, const float* __restrict__ binit,
    float* __restrict__ gic, float* __restrict__ ric, float* __restrict__ s0) {
  __shared__ float cil[256], h0l[256];
  const int b = blockIdx.x, tid = threadIdx.x;
  cil[tid] = ci[b * 256 + tid];
  h0l[tid] = h[(long)b * 2048 * 256 + tid];
  __syncthreads();
  const int k = tid;
  #pragma unroll
  for (int g = 0; g < 3; ++g) {
    float a = bihg[g * 256 + k] + (g < 2 ? bhhg[g * 256 + k] : 0.f);
    const float* wp = Wihg + (long)(g * 256 + k) * 384;
    for (int d = 0; d < 256; d += 4) {
      float4 w4 = *(const float4*)(wp + d);
      a += cil[d] * w4.x + cil[d + 1] * w4.y + cil[d + 2] * w4.z + cil[d + 3] * w4.w;
    }
    gic[b * 768 + g * 256 + k] = a;
  }
  {
    float a = binit[k];
    const float* wp = Winit + (long)k * 256;
    for (int d = 0; d < 256; d += 4) {
      float4 w4 = *(const float4*)(wp + d);
      a += h0l[d] * w4.x + h0l[d + 1] * w4.y + h0l[d + 2] * w4.z + h0l[d + 3] * w4.w;
    }
    s0[b * 256 + k] = fast_tanh(a);
  }
  if (tid < 128) {
    int m = tid;
    float a = bihr[m] + bhhr[m];
    const float* wp = Wihr + (long)m * 512;
    for (int d = 0; d < 256; d += 4) {
      float4 w4 = *(const float4*)(wp + d);
      a += cil[d] * w4.x + cil[d + 1] * w4.y + cil[d + 2] * w4.z + cil[d + 3] * w4.w;
    }
    ric[b * 128 + m] = a;
  }
}

// ---------------- K4: the 64-step recurrence, one block per batch ----------------
__global__ __launch_bounds__(512) void k_loop(
    const float* __restrict__ gic, const float* __restrict__ ric,
    const float* __restrict__ s0w, const float* __restrict__ bhhg,
    const float* __restrict__ GW, const float* __restrict__ RWS,
    const float* __restrict__ RWY,
    float* __restrict__ out) {
  __shared__ float sbuf[2][256];
  __shared__ float ybuf[2][128];
  __shared__ float gicl[768];
  __shared__ float ricl[128];
  __shared__ float bnl[256];
  __shared__ float part[4][256];
  __shared__ float lpart[3][128];
  __shared__ float red[2][2];
  const int tid = threadIdx.x;
  const int b = blockIdx.x;
  gicl[tid] = gic[b * 768 + tid];
  if (tid < 256) gicl[512 + tid] = gic[b * 768 + 512 + tid];
  if (tid < 128) ricl[tid] = ric[b * 128 + tid];
  if (tid < 256) bnl[tid] = bhhg[512 + tid];
  if (tid < 256) sbuf[0][tid] = s0w[b * 256 + tid];
  if (tid < 128) ybuf[0][tid] = 0.f;
  __syncthreads();

  for (int step = 0; step < OL; ++step) {
    const float* scur = sbuf[step & 1];
    float* snew = sbuf[(step & 1) ^ 1];
    const float* ycur = ybuf[step & 1];
    float* ynew = ybuf[(step & 1) ^ 1];
    const int half = tid >> 8;
    const int k = tid & 255;
    float pr = 0.f, pz = 0.f, pnh = 0.f, pni = 0.f;
    {
      // s-part: j in [half*128, half*128+128), GW[j][k][4]
      const float4* gw = (const float4*)GW + ((long)(half * 128) << 8) + k;
      #pragma unroll 8
      for (int j = 0; j < 128; ++j) {
        float sj = scur[half * 128 + j];
        float4 wv = gw[(long)j << 8];
        pr += sj * wv.x; pz += sj * wv.y; pnh += sj * wv.z;
      }
      // y-part: jg = 256 + half*64 + j
      const float4* gy = (const float4*)GW + ((long)(256 + half * 64) << 8) + k;
      #pragma unroll 8
      for (int j = 0; j < 64; ++j) {
        float yj = ycur[half * 64 + j];
        float4 wv = gy[(long)j << 8];
        pr += yj * wv.x; pz += yj * wv.y; pni += yj * wv.z;
      }
    }
    if (half == 1) { part[0][k] = pr; part[1][k] = pz; part[2][k] = pnh; part[3][k] = pni; }
    __syncthreads();
    if (half == 0) {
      float R  = fast_sigmoid(pr + part[0][k] + gicl[k]);
      float Z  = fast_sigmoid(pz + part[1][k] + gicl[256 + k]);
      float hn = pnh + part[2][k] + bnl[k];
      float in_ = pni + part[3][k] + gicl[512 + k];
      float N = fast_tanh(in_ + R * hn);
      snew[k] = (1.f - Z) * N + Z * scur[k];
    }
    __syncthreads();
    // ---- output RNN logits ----
    const int m = tid & 127;
    const int g = tid >> 7;
    float acc = 0.f;
    if (g == 0) {
      const float* p = RWS + m;
      #pragma unroll 8
      for (int j = 0; j < 128; ++j) { acc += snew[j] * p[0]; p += 128; }
    } else if (g == 1) {
      const float* p = RWS + 128 * 128 + m;
      #pragma unroll 8
      for (int j = 128; j < 256; ++j) { acc += snew[j] * p[0]; p += 128; }
    } else if (g == 2) {
      const float* p = RWY + m;
      #pragma unroll 8
      for (int j = 0; j < 64; ++j) { acc += ycur[j] * p[0]; p += 128; }
    } else {
      const float* p = RWY + 64 * 128 + m;
      #pragma unroll 8
      for (int j = 64; j < 128; ++j) { acc += ycur[j] * p[0]; p += 128; }
    }
    if (g > 0) lpart[g - 1][m] = acc;
    __syncthreads();
    float L = 0.f, e = 0.f;
    if (g == 0) {
      // tanh is part of _rnn_cell — softmax is over tanh'd logits!
      L = fast_tanh(acc + lpart[0][m] + lpart[1][m] + lpart[2][m] + ricl[m]);
      float mx = L;
      #pragma unroll
      for (int d = 32; d >= 1; d >>= 1) mx = fmaxf(mx, __shfl_xor(mx, d));
      if ((tid & 63) == 0) red[0][tid >> 6] = mx;
    }
    __syncthreads();
    if (g == 0) {
      float M = fmaxf(red[0][0], red[0][1]);
      e = __expf(L - M);
      float s = e;
      #pragma unroll
      for (int d = 32; d >= 1; d >>= 1) s += __shfl_xor(s, d);
      if ((tid & 63) == 0) red[1][tid >> 6] = s;
    }
    __syncthreads();
    if (g == 0) {
      float S = red[1][0] + red[1][1];
      float yv = e / S;
      ynew[m] = yv;
      out[((long)b * OL + step) * DO_ + m] = yv;
    }
    __syncthreads();
  }
}

extern "C" void kernel_launch(void* const* d_in, const int* in_sizes, int n_in,
                              void* d_out, int out_size, void* d_ws, size_t ws_size,
                              hipStream_t stream) {
  const float* h     = (const float*)d_in[0];
  const float* Wha   = (const float*)d_in[1];
  const float* Wa    = (const float*)d_in[4];
  const float* Winit = (const float*)d_in[5];
  const float* binit = (const float*)d_in[6];
  const float* Wihg  = (const float*)d_in[7];
  const float* Whhg  = (const float*)d_in[8];
  const float* bihg  = (const float*)d_in[9];
  const float* bhhg  = (const float*)d_in[10];
  const float* Wihr  = (const float*)d_in[11];
  const float* Whhr  = (const float*)d_in[12];
  const float* bihr  = (const float*)d_in[13];
  const float* bhhr  = (const float*)d_in[14];
  float* ws  = (float*)d_ws;
  float* out = (float*)d_out;
  ushort_t* us = (ushort_t*)(ws + O_US);

  k_prep<<<dim3(1984), dim3(256), 0, stream>>>(Wha, Whhg, Wihg, Wihr, Whhr, ws, us);
  k_twh<<<dim3(2048), dim3(256), 0, stream>>>(h, us + U_WB, Wa, ws + O_TWH);
  k_stats<<<dim3(64), dim3(256), 0, stream>>>(ws + O_TWH, ws + O_RMAX, ws + O_RDEN);
  k_cipart<<<dim3(1024), dim3(256), 0, stream>>>(h, ws + O_TWH, ws + O_RMAX, ws + O_CIP);
  k_cired<<<dim3(64), dim3(256), 0, stream>>>(ws + O_CIP, ws + O_RDEN, ws + O_CI);
  k_const<<<dim3(64), dim3(256), 0, stream>>>(h, ws + O_CI, Wihg, bihg, bhhg,
                                              Wihr, bihr, bhhr, Winit, binit,
                                              ws + O_GIC, ws + O_RIC, ws + O_S0);
  k_loop<<<dim3(64), dim3(512), 0, stream>>>(ws + O_GIC, ws + O_RIC, ws + O_S0, bhhg,
                                             ws + F_GW, ws + F_RWS, ws + F_RWY,
                                             out);
}

// Round 3
// 732.045 us; speedup vs baseline: 1.5086x; 1.5086x over previous
//
#include <hip/hip_runtime.h>
#include <cstdint>

typedef unsigned short ushort_t;
typedef __attribute__((ext_vector_type(8))) short short8;
typedef __attribute__((ext_vector_type(4))) float f4;

#define BB   64
#define TT   2048
#define DD   256
#define DO_  128
#define OL   64

// ---- workspace layout (float indices) ----
#define O_TWH   0
#define O_RMAX  131072
#define O_RDEN  131136
#define O_CIP   131200            // 64*16*256 = 262144
#define O_CI    393344            // 64*256
#define O_GIC   409728            // 64*768
#define O_RIC   458880            // 64*128
#define O_S0    467072            // 64*256
#define P_WR    483456            // uint[384][128] bf16x2 gate-r plane = 49152 slots
#define P_WZ    532608            // gate-z plane
#define P_WN    581760            // gate-n plane (j<256: h_n ; j>=256: i_n y-part)
#define F_RWS2  630912            // fp32 [m<128][j<256] = W_ih_r[m][256+j] = 32768
#define F_RWY2  663680            // fp32 [m<128][jy<128] = W_hh_r[m][jy] = 16384
#define O_US    680064            // ushort region (bf16 W_h_a)
#define U_WB    0                 // 256*256 bf16 of W_h_a (row-major)

static __device__ __forceinline__ ushort_t f2bf(float f) {
  union { float f; uint32_t u; } v; v.f = f;
  uint32_t u = v.u;
  u += 0x7FFFu + ((u >> 16) & 1u);   // RNE (inputs are finite normals)
  return (ushort_t)(u >> 16);
}
static __device__ __forceinline__ float bflo(uint32_t u) {
  union { uint32_t u; float f; } v; v.u = u << 16; return v.f;
}
static __device__ __forceinline__ float bfhi(uint32_t u) {
  union { uint32_t u; float f; } v; v.u = u & 0xffff0000u; return v.f;
}
static __device__ __forceinline__ float fast_tanh(float x) {
  float e = __expf(2.f * x);
  return 1.f - 2.f / (e + 1.f);
}
static __device__ __forceinline__ float fast_sigmoid(float x) {
  return 1.f / (1.f + __expf(-x));
}

// ---------------- K0: weight repack ----------------
// items: 65536 (Wha bf16) + 3*49152 (gate planes) + 32768 (RWS2) + 16384 (RWY2) = 262144
__global__ __launch_bounds__(256) void k_prep(const float* __restrict__ Wha,
    const float* __restrict__ Whhg, const float* __restrict__ Wihg,
    const float* __restrict__ Wihr, const float* __restrict__ Whhr,
    float* __restrict__ ws, ushort_t* __restrict__ us) {
  int idx = blockIdx.x * 256 + threadIdx.x;   // grid exactly 1024
  if (idx < 65536) {
    us[U_WB + idx] = f2bf(Wha[idx]);
    return;
  }
  if (idx < 212992) {
    // gate planes: plane p, item i -> [j][kp] packed bf16 pair (k0=2kp lo, k1 hi)
    int q = idx - 65536;
    int p = q / 49152;            // 0:r 1:z 2:n
    int i = q - p * 49152;
    int j = i >> 7, kp = i & 127;
    int k0 = kp * 2, k1 = k0 + 1;
    int ro = p * 256;             // gate row offset
    float v0, v1;
    if (j < 256) {                // s-input rows from W_hh_g
      v0 = Whhg[(ro + k0) * 256 + j];
      v1 = Whhg[(ro + k1) * 256 + j];
    } else {                      // y-input rows from W_ih_g (cols 256..384)
      int jy = j - 256;
      v0 = Wihg[(ro + k0) * 384 + 256 + jy];
      v1 = Wihg[(ro + k1) * 384 + 256 + jy];
    }
    uint32_t packed = ((uint32_t)f2bf(v1) << 16) | (uint32_t)f2bf(v0);
    ((uint32_t*)(ws + P_WR))[p * 49152 + i] = packed;
    return;
  }
  if (idx < 245760) {
    int i = idx - 212992; int m = i >> 8, j = i & 255;
    ws[F_RWS2 + i] = Wihr[m * 512 + 256 + j];
  } else {
    int i = idx - 245760; int m = i >> 7, jy = i & 127;
    ws[F_RWY2 + i] = Whhr[m * 128 + jy];
  }
}

// ---------------- K1: twh[b,t] = sum_h tanh(h.Wha^T) * wa1 (MFMA) ----------------
__global__ __launch_bounds__(256) void k_twh(const float* __restrict__ h,
                                             const ushort_t* __restrict__ Wb,
                                             const float* __restrict__ Wa,
                                             float* __restrict__ twh) {
  __shared__ __align__(16) ushort_t alds[64 * 264];
  __shared__ float walds[256];
  const int tid = threadIdx.x;
  const long rowbase = (long)blockIdx.x * 64;
  walds[tid] = Wa[tid];
  for (int it = 0; it < 8; ++it) {
    int q = it * 256 + tid;
    int r = q >> 5;
    int c8 = q & 31;
    const float* src = h + (rowbase + r) * 256 + c8 * 8;
    float4 a = *(const float4*)(src);
    float4 b = *(const float4*)(src + 4);
    union { ushort_t u[8]; short8 v; } t;
    t.u[0]=f2bf(a.x); t.u[1]=f2bf(a.y); t.u[2]=f2bf(a.z); t.u[3]=f2bf(a.w);
    t.u[4]=f2bf(b.x); t.u[5]=f2bf(b.y); t.u[6]=f2bf(b.z); t.u[7]=f2bf(b.w);
    *(short8*)&alds[r * 264 + c8 * 8] = t.v;
  }
  __syncthreads();
  const int l = tid & 63, w = tid >> 6;
  const int cres = l & 15, kg = l >> 4;
  f4 acc[16];
  #pragma unroll
  for (int f = 0; f < 16; ++f) acc[f] = (f4){0.f, 0.f, 0.f, 0.f};
  const int arow = 16 * w + cres;
  #pragma unroll
  for (int ks = 0; ks < 8; ++ks) {
    short8 af = *(const short8*)&alds[arow * 264 + ks * 32 + kg * 8];
    const ushort_t* bp = Wb + ks * 32 + kg * 8 + cres * 256;
    #pragma unroll
    for (int f = 0; f < 16; ++f) {
      short8 bf = *(const short8*)(bp + f * 16 * 256);
      acc[f] = __builtin_amdgcn_mfma_f32_16x16x32_bf16(af, bf, acc[f], 0, 0, 0);
    }
  }
  float t4[4] = {0.f, 0.f, 0.f, 0.f};
  #pragma unroll
  for (int f = 0; f < 16; ++f) {
    float wa = walds[16 * f + cres];
    #pragma unroll
    for (int r = 0; r < 4; ++r) t4[r] += fast_tanh(acc[f][r]) * wa;
  }
  #pragma unroll
  for (int m = 1; m <= 8; m <<= 1) {
    #pragma unroll
    for (int r = 0; r < 4; ++r) t4[r] += __shfl_xor(t4[r], m);
  }
  if (cres == 0) {
    #pragma unroll
    for (int r = 0; r < 4; ++r)
      twh[rowbase + 16 * w + kg * 4 + r] = t4[r];
  }
}

// ---------------- K2a: per-batch softmax stats over T ----------------
__global__ __launch_bounds__(256) void k_stats(const float* __restrict__ twh,
                                               float* __restrict__ rmax,
                                               float* __restrict__ rden) {
  __shared__ float redm[4], reds[4];
  const int b = blockIdx.x, tid = threadIdx.x;
  float v[8];
  #pragma unroll
  for (int j = 0; j < 8; ++j) v[j] = twh[b * 2048 + tid + j * 256];
  float mx = v[0];
  #pragma unroll
  for (int j = 1; j < 8; ++j) mx = fmaxf(mx, v[j]);
  #pragma unroll
  for (int d = 32; d >= 1; d >>= 1) mx = fmaxf(mx, __shfl_xor(mx, d));
  if ((tid & 63) == 0) redm[tid >> 6] = mx;
  __syncthreads();
  float M = fmaxf(fmaxf(redm[0], redm[1]), fmaxf(redm[2], redm[3]));
  float s = 0.f;
  #pragma unroll
  for (int j = 0; j < 8; ++j) s += __expf(v[j] - M);
  #pragma unroll
  for (int d = 32; d >= 1; d >>= 1) s += __shfl_xor(s, d);
  if ((tid & 63) == 0) reds[tid >> 6] = s;
  __syncthreads();
  if (tid == 0) { rmax[b] = M; rden[b] = reds[0] + reds[1] + reds[2] + reds[3]; }
}

// ---------------- K2b: partial ci over t-slices ----------------
__global__ __launch_bounds__(256) void k_cipart(const float* __restrict__ h,
                                                const float* __restrict__ twh,
                                                const float* __restrict__ rmax,
                                                float* __restrict__ cipart) {
  __shared__ float p[128];
  const int b = blockIdx.x >> 4, ts = blockIdx.x & 15;
  const int tid = threadIdx.x;
  const int t0 = ts * 128;
  if (tid < 128) p[tid] = __expf(twh[b * 2048 + t0 + tid] - rmax[b]);
  __syncthreads();
  float acc = 0.f;
  const float* hp = h + ((long)(b * 2048 + t0)) * 256 + tid;
  #pragma unroll 8
  for (int i = 0; i < 128; ++i) { acc += p[i] * hp[0]; hp += 256; }
  cipart[(b * 16 + ts) * 256 + tid] = acc;
}

// ---------------- K2c: reduce partials -> ci ----------------
__global__ __launch_bounds__(256) void k_cired(const float* __restrict__ cipart,
                                               const float* __restrict__ rden,
                                               float* __restrict__ ci) {
  const int b = blockIdx.x, d = threadIdx.x;
  float a = 0.f;
  #pragma unroll
  for (int ts = 0; ts < 16; ++ts) a += cipart[(b * 16 + ts) * 256 + d];
  ci[b * 256 + d] = a / rden[b];
}

// ---------------- K3: per-batch constants (gi_c, ri_c, s0) ----------------
__global__ __launch_bounds__(256) void k_const(const float* __restrict__ h,
    const float* __restrict__ ci,
    const float* __restrict__ Wihg, const float* __restrict__ bihg,
    const float* __restrict__ bhhg,
    const float* __restrict__ Wihr, const float* __restrict__ bihr,
    const float* __restrict__ bhhr,
    const float* __restrict__ Winit, const float* __restrict__ binit,
    float* __restrict__ gic, float* __restrict__ ric, float* __restrict__ s0) {
  __shared__ float cil[256], h0l[256];
  const int b = blockIdx.x, tid = threadIdx.x;
  cil[tid] = ci[b * 256 + tid];
  h0l[tid] = h[(long)b * 2048 * 256 + tid];
  __syncthreads();
  const int k = tid;
  #pragma unroll
  for (int g = 0; g < 3; ++g) {
    float a = bihg[g * 256 + k] + (g < 2 ? bhhg[g * 256 + k] : 0.f);
    const float* wp = Wihg + (long)(g * 256 + k) * 384;
    for (int d = 0; d < 256; d += 4) {
      float4 w4 = *(const float4*)(wp + d);
      a += cil[d] * w4.x + cil[d + 1] * w4.y + cil[d + 2] * w4.z + cil[d + 3] * w4.w;
    }
    gic[b * 768 + g * 256 + k] = a;
  }
  {
    float a = binit[k];
    const float* wp = Winit + (long)k * 256;
    for (int d = 0; d < 256; d += 4) {
      float4 w4 = *(const float4*)(wp + d);
      a += h0l[d] * w4.x + h0l[d + 1] * w4.y + h0l[d + 2] * w4.z + h0l[d + 3] * w4.w;
    }
    s0[b * 256 + k] = fast_tanh(a);
  }
  if (tid < 128) {
    int m = tid;
    float a = bihr[m] + bhhr[m];
    const float* wp = Wihr + (long)m * 512;
    for (int d = 0; d < 256; d += 4) {
      float4 w4 = *(const float4*)(wp + d);
      a += cil[d] * w4.x + cil[d + 1] * w4.y + cil[d + 2] * w4.z + cil[d + 3] * w4.w;
    }
    ric[b * 128 + m] = a;
  }
}

// ---------------- K4: the 64-step recurrence, one block per batch ----------------
// 1024 threads = 128 k-pairs x 8 j-slices. Gate weights bf16 (packed pairs),
// RNN weights fp32 (direct output path). Per-step L2 traffic 0.79 MB/block.
__global__ __launch_bounds__(1024) void k_loop(
    const float* __restrict__ gic, const float* __restrict__ ric,
    const float* __restrict__ s0w, const float* __restrict__ bhhg,
    const uint32_t* __restrict__ WR, const uint32_t* __restrict__ WZ,
    const uint32_t* __restrict__ WN,
    const float* __restrict__ RWS2, const float* __restrict__ RWY2,
    float* __restrict__ out) {
  __shared__ float sbuf[2][256];
  __shared__ float ybuf[2][128];
  __shared__ float gicl[768];
  __shared__ float ricl[128];
  __shared__ float bnl[256];
  __shared__ float gpart[8][128][9];   // stride-9 pad: conflict-free reduce
  __shared__ float gsum[1024];
  __shared__ float rpart[8][128];
  __shared__ float red[2];
  const int tid = threadIdx.x;
  const int b = blockIdx.x;
  if (tid < 768) gicl[tid] = gic[b * 768 + tid];
  else if (tid < 896) ricl[tid - 768] = ric[b * 128 + tid - 768];
  if (tid < 256) { bnl[tid] = bhhg[512 + tid]; sbuf[0][tid] = s0w[b * 256 + tid]; }
  if (tid < 128) ybuf[0][tid] = 0.f;
  __syncthreads();

  const int kp = tid & 127, jq = tid >> 7;
  // gate-plane pointers (j-major, stride 128 uints)
  const uint32_t* wrs = WR + (jq * 32) * 128 + kp;
  const uint32_t* wzs = WZ + (jq * 32) * 128 + kp;
  const uint32_t* wns = WN + (jq * 32) * 128 + kp;
  const uint32_t* wry = WR + (256 + jq * 16) * 128 + kp;
  const uint32_t* wzy = WZ + (256 + jq * 16) * 128 + kp;
  const uint32_t* wny = WN + (256 + jq * 16) * 128 + kp;
  const int m = tid & 127;

  for (int step = 0; step < OL; ++step) {
    const float* scur = sbuf[step & 1];
    float* snew = sbuf[(step & 1) ^ 1];
    const float* ycur = ybuf[step & 1];
    float* ynew = ybuf[(step & 1) ^ 1];

    // ---- phase G: gate GEMV partials ----
    float pr0 = 0.f, pr1 = 0.f, pz0 = 0.f, pz1 = 0.f;
    float pa0 = 0.f, pa1 = 0.f, pb0 = 0.f, pb1 = 0.f;
    {
      const float* sc = scur + jq * 32;
      #pragma unroll 8
      for (int j = 0; j < 32; ++j) {
        float sj = sc[j];
        uint32_t ur = wrs[j * 128], uz = wzs[j * 128], un = wns[j * 128];
        pr0 += sj * bflo(ur); pr1 += sj * bfhi(ur);
        pz0 += sj * bflo(uz); pz1 += sj * bfhi(uz);
        pa0 += sj * bflo(un); pa1 += sj * bfhi(un);
      }
      const float* yc = ycur + jq * 16;
      #pragma unroll 8
      for (int j = 0; j < 16; ++j) {
        float yj = yc[j];
        uint32_t ur = wry[j * 128], uz = wzy[j * 128], un = wny[j * 128];
        pr0 += yj * bflo(ur); pr1 += yj * bfhi(ur);
        pz0 += yj * bflo(uz); pz1 += yj * bfhi(uz);
        pb0 += yj * bflo(un); pb1 += yj * bfhi(un);
      }
      float* gp = &gpart[jq][kp][0];
      gp[0] = pr0; gp[1] = pr1; gp[2] = pz0; gp[3] = pz1;
      gp[4] = pa0; gp[5] = pa1; gp[6] = pb0; gp[7] = pb1;
    }
    __syncthreads();
    // ---- reduce partials over jq ----
    {
      const int slot = tid >> 8, k = tid & 255;
      const int e = slot * 2 + (k & 1), kp2 = k >> 1;
      float s = 0.f;
      #pragma unroll
      for (int q = 0; q < 8; ++q) s += gpart[q][kp2][e];
      gsum[slot * 256 + k] = s;
    }
    __syncthreads();
    // ---- GRU update ----
    if (tid < 256) {
      const int k = tid;
      float R   = fast_sigmoid(gsum[k] + gicl[k]);
      float Z   = fast_sigmoid(gsum[256 + k] + gicl[256 + k]);
      float hn  = gsum[512 + k] + bnl[k];
      float in_ = gsum[768 + k] + gicl[512 + k];
      float N = fast_tanh(in_ + R * hn);
      snew[k] = (1.f - Z) * N + Z * scur[k];
    }
    __syncthreads();
    // ---- phase R: RNN logits (fp32 weights) ----
    {
      float acc = 0.f;
      const float4* ps = (const float4*)(RWS2 + m * 256 + jq * 32);
      const float* sn = snew + jq * 32;
      #pragma unroll
      for (int j4 = 0; j4 < 8; ++j4) {
        float4 w = ps[j4];
        acc += sn[j4 * 4] * w.x + sn[j4 * 4 + 1] * w.y +
               sn[j4 * 4 + 2] * w.z + sn[j4 * 4 + 3] * w.w;
      }
      const float4* py = (const float4*)(RWY2 + m * 128 + jq * 16);
      const float* yc2 = ycur + jq * 16;
      #pragma unroll
      for (int j4 = 0; j4 < 4; ++j4) {
        float4 w = py[j4];
        acc += yc2[j4 * 4] * w.x + yc2[j4 * 4 + 1] * w.y +
               yc2[j4 * 4 + 2] * w.z + yc2[j4 * 4 + 3] * w.w;
      }
      rpart[jq][m] = acc;
    }
    __syncthreads();
    // ---- tanh + softmax (no max pass: tanh bounds logits to [-1,1]) ----
    float e = 0.f;
    if (tid < 128) {
      float L = ricl[m];
      #pragma unroll
      for (int q = 0; q < 8; ++q) L += rpart[q][m];
      L = fast_tanh(L);
      e = __expf(L);
      float s = e;
      #pragma unroll
      for (int d = 32; d >= 1; d >>= 1) s += __shfl_xor(s, d);
      if ((tid & 63) == 0) red[tid >> 6] = s;
    }
    __syncthreads();
    if (tid < 128) {
      float S = red[0] + red[1];
      float yv = e / S;
      ynew[m] = yv;
      out[((long)b * OL + step) * DO_ + m] = yv;
    }
    __syncthreads();
  }
}

extern "C" void kernel_launch(void* const* d_in, const int* in_sizes, int n_in,
                              void* d_out, int out_size, void* d_ws, size_t ws_size,
                              hipStream_t stream) {
  const float* h     = (const float*)d_in[0];
  const float* Wha   = (const float*)d_in[1];
  const float* Wa    = (const float*)d_in[4];
  const float* Winit = (const float*)d_in[5];
  const float* binit = (const float*)d_in[6];
  const float* Wihg  = (const float*)d_in[7];
  const float* Whhg  = (const float*)d_in[8];
  const float* bihg  = (const float*)d_in[9];
  const float* bhhg  = (const float*)d_in[10];
  const float* Wihr  = (const float*)d_in[11];
  const float* Whhr  = (const float*)d_in[12];
  const float* bihr  = (const float*)d_in[13];
  const float* bhhr  = (const float*)d_in[14];
  float* ws  = (float*)d_ws;
  float* out = (float*)d_out;
  ushort_t* us = (ushort_t*)(ws + O_US);

  k_prep<<<dim3(1024), dim3(256), 0, stream>>>(Wha, Whhg, Wihg, Wihr, Whhr, ws, us);
  k_twh<<<dim3(2048), dim3(256), 0, stream>>>(h, us + U_WB, Wa, ws + O_TWH);
  k_stats<<<dim3(64), dim3(256), 0, stream>>>(ws + O_TWH, ws + O_RMAX, ws + O_RDEN);
  k_cipart<<<dim3(1024), dim3(256), 0, stream>>>(h, ws + O_TWH, ws + O_RMAX, ws + O_CIP);
  k_cired<<<dim3(64), dim3(256), 0, stream>>>(ws + O_CIP, ws + O_RDEN, ws + O_CI);
  k_const<<<dim3(64), dim3(256), 0, stream>>>(h, ws + O_CI, Wihg, bihg, bhhg,
                                              Wihr, bihr, bhhr, Winit, binit,
                                              ws + O_GIC, ws + O_RIC, ws + O_S0);
  k_loop<<<dim3(64), dim3(1024), 0, stream>>>(ws + O_GIC, ws + O_RIC, ws + O_S0, bhhg,
                                              (const uint32_t*)(ws + P_WR),
                                              (const uint32_t*)(ws + P_WZ),
                                              (const uint32_t*)(ws + P_WN),
                                              ws + F_RWS2, ws + F_RWY2,
                                              out);
}